// Round 16
// baseline (299.502 us; speedup 1.0000x reference)
//
#include <hip/hip_runtime.h>
#include <hip/hip_bf16.h>
#include <math.h>

// Problem constants
#define B_    32
#define IC    512
#define OC    256
#define HW    32
#define OHW   64

// ws layout (new split path):
//   xcl at 0:         bf16 [32][34][34][512] = 37,879,808
//   A2  at 37879808:  bf16 [4][256][2048]    =  4,194,304
//   Y   at 42074112:  bf16 [4][32][34][34][256] = 75,890,688
//   total 117,964,800
#define WS_A2_OFF 37879808ull
#define WS_Y_OFF  42074112ull
#define WS_NEED   117964800ull
// fallback (fused) path: Amat at 37879808 (9.4 MB), total 47,316,992
#define WS_AMAT_OFF 37879808ull

typedef __attribute__((ext_vector_type(8))) short short8;
typedef __attribute__((ext_vector_type(4))) float f32x4;
typedef __attribute__((ext_vector_type(2))) float f32x2;

#define GPTR(x) ((const __attribute__((address_space(1))) char*)(x))
#define LPTR(x) ((__attribute__((address_space(3))) char*)(x))

// ---------------------------------------------------------------------------
// x (fp32 NCHW) -> xcl (bf16, [b][34][34][512], zero halo). Shared by paths.
__global__ __launch_bounds__(256) void xprep(const float* __restrict__ x,
                                             __hip_bfloat16* __restrict__ xcl) {
    int blk = blockIdx.x;            // 32*34 blocks
    int b = blk / 34, h = blk % 34;
    __hip_bfloat16* orow = xcl + (size_t)(b * 34 + h) * 34 * 512;
    int t = threadIdx.x;
    bool hin = (h >= 1 && h <= 32);

    for (int i = t; i < 2 * 512; i += 256) {
        int wsel = i >> 9, ic = i & 511;
        orow[(size_t)(wsel * 33) * 512 + ic] = __float2bfloat16(0.f);
    }

    __shared__ float ls[16][33];
    int icl_r = t >> 5, wv_r = t & 31;
    int wv_w = t >> 3, icl_w = t & 7;

    for (int ic0 = 0; ic0 < 512; ic0 += 16) {
        __syncthreads();
#pragma unroll
        for (int pp = 0; pp < 2; ++pp) {
            int icll = icl_r + pp * 8;
            float v = 0.f;
            if (hin) v = x[(((size_t)b * IC + ic0 + icll) * HW + (h - 1)) * HW + wv_r];
            ls[icll][wv_r] = v;
        }
        __syncthreads();
#pragma unroll
        for (int pp = 0; pp < 2; ++pp) {
            int icll = icl_w + pp * 8;
            orow[(size_t)(wv_w + 1) * 512 + ic0 + icll] = __float2bfloat16(ls[icll][wv_w]);
        }
    }
}

// ===========================================================================
// NEW SPLIT PATH
// Stage 0: weight prep. A2[p][oc][kt*512+ic] = gain * w[oc][ic][a+2di][b+2dj]
//   p=(a,b); tap lists: p0:(di,dj)=kt(2b); p1:di=kt,dj=0; p2:di=0,dj=kt; p3:(0,0)
__global__ __launch_bounds__(256) void wtrans2(const float* __restrict__ w,
                                               __hip_bfloat16* __restrict__ A2) {
    int t = blockIdx.x * blockDim.x + threadIdx.x;  // 131072
    int ic = t & 511, oc = t >> 9;
    const float gain = 1.0f / sqrtf((float)(IC * 9));
    const float* wp = w + ((size_t)oc * IC + ic) * 9;
    float wl[3][3];
#pragma unroll
    for (int i = 0; i < 3; ++i)
#pragma unroll
        for (int j = 0; j < 3; ++j) wl[i][j] = wp[i * 3 + j] * gain;

    auto put = [&](int p, int kt, float v) {
        A2[((size_t)(p * 256 + oc) * 2048) + kt * 512 + ic] = __float2bfloat16(v);
    };
    // p0 (a=0,b=0): taps w[2di][2dj]
    put(0, 0, wl[0][0]); put(0, 1, wl[0][2]); put(0, 2, wl[2][0]); put(0, 3, wl[2][2]);
    // p1 (a=0,b=1): w[2kt][1]
    put(1, 0, wl[0][1]); put(1, 1, wl[2][1]);
    // p2 (a=1,b=0): w[1][2kt]
    put(2, 0, wl[1][0]); put(2, 1, wl[1][2]);
    // p3 (a=1,b=1): w[1][1]
    put(3, 0, wl[1][1]);
}

// Stage 1: per-parity implicit GEMM. C[M=256 oc][N=36992=(b,sy,ty)] per parity.
// y[2s+a,2t+b] = sum_{di,dj} x[s-di,t-dj]*w[a+2di,b+2dj]; Yidx sy=s+1,ty=t+1.
// Pad rows (sy=0 etc.) come free from xcl's zero halo. Writes Y bf16.
// Structure: M=256 x N=128 tile, BK=32, 8 waves (4M x 2N), ring-4 LDS 96 KB,
// counted vmcnt(3), R4 zero-conflict swizzle, NT per parity {64,32,32,16}.
__global__ __launch_bounds__(512) void gemm1(const __hip_bfloat16* __restrict__ A2,
                                             const __hip_bfloat16* __restrict__ xcl,
                                             __hip_bfloat16* __restrict__ Y) {
    __shared__ __align__(1024) char lds[4 * 24576];

    int bid = blockIdx.x;            // 1160 launched; 1156 useful
    int x_ = bid & 7, j_ = bid >> 3; // bijective XCD slabs (m204 pattern)
    int idx = (x_ < 4) ? (x_ * 145 + j_) : (580 + (x_ - 4) * 144 + j_);
    if (x_ < 4) { if (j_ >= 145) return; } else { if (j_ >= 144) return; }
    if (idx >= 1156) return;
    int p = idx & 3;                 // parity: consecutive idx share nt -> same XCD
    int nt = idx >> 2;               // 0..288
    const int NT = (p == 0) ? 64 : (p == 3) ? 16 : 32;

    int tid = threadIdx.x;
    int wid = tid >> 6;
    int lane = tid & 63;
    int wr = wid >> 1;               // 0..3  M quarter (64 rows)
    int wc = wid & 1;                // 0..1  N half (64 cols)
    int q = lane >> 4;
    int lr = lane & 15;

    // staging constants
    int lrow = (lane >> 2);          // 0..15
    int sgl = (lane & 3) ^ ((lane >> 3) & 3);   // slot^((row>>1)&3), row=wid*16+lrow

    // A rows: i*128 + wid*16 + lrow ; pitch 4096 B
    size_t aoff[2];
#pragma unroll
    for (int i = 0; i < 2; ++i)
        aoff[i] = (size_t)(p * 256 + i * 128 + wid * 16 + lrow) * 4096 + sgl * 16;

    // B row: nloc = wid*16+lrow ; 4 tap base addresses (clamped)
    int nloc = wid * 16 + lrow;
    int n_ = nt * 128 + nloc;
    int bI = n_ / 1156, r_ = n_ - bI * 1156;
    int sy = r_ / 34, ty = r_ - sy * 34;
    int bt[2][2];
#pragma unroll
    for (int di = 0; di < 2; ++di)
#pragma unroll
        for (int dj = 0; dj < 2; ++dj) {
            int rr = sy - di; if (rr < 0) rr = 0;
            int cc = ty - dj; if (cc < 0) cc = 0;
            bt[di][dj] = ((bI * 34 + rr) * 34 + cc) * 1024 + sgl * 16;
        }

    const char* GA = (const char*)A2;
    const char* GB = (const char*)xcl;
    int dA0 = wid * 1024 + lane * 16 - lane * 16;  // dest bases (lane*16 by HW)
    // (dest args below add wid*1024 only)

    // ds_read bases
    int qs = (q ^ ((lr >> 1) & 3)) << 4;
    int A0 = (wr * 64 + lr) * 64 + qs;            // + mi*1024
    int B0 = 16384 + (wc * 64 + lr) * 64 + qs;    // + ni*1024

    f32x4 acc[4][4];
#pragma unroll
    for (int mi = 0; mi < 4; ++mi)
#pragma unroll
        for (int ni = 0; ni < 4; ++ni) acc[mi][ni] = (f32x4){0.f, 0.f, 0.f, 0.f};

    auto STAGE = [&](int ks, int bufi) {   // 3 loads/thread: A x2, B x1
        int tap = ks >> 4, icc = ks & 15;
        int di, dj;
        if (p == 0) { di = tap >> 1; dj = tap & 1; }
        else if (p == 1) { di = tap; dj = 0; }
        else if (p == 2) { di = 0; dj = tap; }
        else { di = 0; dj = 0; }
        int bko = (di ? (dj ? bt[1][1] : bt[1][0]) : (dj ? bt[0][1] : bt[0][0])) + icc * 64;
        int ao = ks * 64;
        char* L = lds + bufi * 24576;
        __builtin_amdgcn_global_load_lds(GPTR(GA + aoff[0] + ao), LPTR(L + wid * 1024), 16, 0, 0);
        __builtin_amdgcn_global_load_lds(GPTR(GA + aoff[1] + ao), LPTR(L + 8192 + wid * 1024), 16, 0, 0);
        __builtin_amdgcn_global_load_lds(GPTR(GB + bko), LPTR(L + 16384 + wid * 1024), 16, 0, 0);
    };

    STAGE(0, 0);
    STAGE(1, 1);

    for (int t = 0; t < NT; ++t) {
        asm volatile("s_waitcnt vmcnt(3)" ::: "memory");   // tile t landed
        __builtin_amdgcn_s_barrier();
        __builtin_amdgcn_sched_barrier(0);
        STAGE(t + 2 < NT ? t + 2 : NT - 1, (t + 2) & 3);

        const char* Lc = lds + (t & 3) * 24576;
        short8 aF[4], bF[4];
#pragma unroll
        for (int mi = 0; mi < 4; ++mi) aF[mi] = *(const short8*)(Lc + A0 + mi * 1024);
#pragma unroll
        for (int ni = 0; ni < 4; ++ni) bF[ni] = *(const short8*)(Lc + B0 + ni * 1024);

        __builtin_amdgcn_s_setprio(1);
#pragma unroll
        for (int mi = 0; mi < 4; ++mi)
#pragma unroll
            for (int ni = 0; ni < 4; ++ni)
                acc[mi][ni] = __builtin_amdgcn_mfma_f32_16x16x32_bf16(
                    aF[mi], bF[ni], acc[mi][ni], 0, 0, 0);
        __builtin_amdgcn_s_setprio(0);
    }
    asm volatile("s_waitcnt vmcnt(0)" ::: "memory");

    // epilogue: C col = lane&15 (n), row = (lane>>4)*4+reg (oc). ushort4 store.
#pragma unroll
    for (int ni = 0; ni < 4; ++ni) {
        int n = nt * 128 + wc * 64 + ni * 16 + lr;
        int b = n / 1156, r2 = n - b * 1156;
        int syy = r2 / 34, tyy = r2 - syy * 34;
        size_t rowbase = ((size_t)((p * 32 + b) * 34 + syy) * 34 + tyy) * 256;
#pragma unroll
        for (int mi = 0; mi < 4; ++mi) {
            int oc = wr * 64 + mi * 16 + (lane >> 4) * 4;
            ushort4 st;
            __hip_bfloat16 h0 = __float2bfloat16(acc[mi][ni][0]);
            __hip_bfloat16 h1 = __float2bfloat16(acc[mi][ni][1]);
            __hip_bfloat16 h2 = __float2bfloat16(acc[mi][ni][2]);
            __hip_bfloat16 h3 = __float2bfloat16(acc[mi][ni][3]);
            st.x = *reinterpret_cast<unsigned short*>(&h0);
            st.y = *reinterpret_cast<unsigned short*>(&h1);
            st.z = *reinterpret_cast<unsigned short*>(&h2);
            st.w = *reinterpret_cast<unsigned short*>(&h3);
            *reinterpret_cast<ushort4*>((char*)Y + (rowbase + oc) * 2) = st;
        }
    }
}

// Stage 2: depthwise FIR + bias + leaky*sqrt(2). No bounds checks (Y padded).
// out(2u+pm,2v+pn) = (1/16)*sum_{aR,aC} sum_{jr,jc} Y[(aR,aC)][syb+jr][tyb+jc]
//   * R[aR][pm][jr] * R[aC][pn][jc];  RE={{3,1},{1,3}}, RO={{1,3,0},{0,3,1}}
__global__ __launch_bounds__(256) void fir2(const __hip_bfloat16* __restrict__ Y,
                                            const float* __restrict__ bias,
                                            float* __restrict__ out) {
    int bid = blockIdx.x;            // 4096 = b(32) * u(32) * ocq(4)
    int b = bid >> 7, u = (bid >> 2) & 31, ocq = bid & 3;
    int tid = threadIdx.x;
    int oct = tid >> 5, v = tid & 31;
    int ocb = ocq * 64 + oct * 8;

    float o[2][2][8];
#pragma unroll
    for (int pm = 0; pm < 2; ++pm)
#pragma unroll
        for (int pn = 0; pn < 2; ++pn)
#pragma unroll
            for (int k = 0; k < 8; ++k) o[pm][pn][k] = 0.f;

    const int RE[2][2] = {{3, 1}, {1, 3}};
    const int RO[2][3] = {{1, 3, 0}, {0, 3, 1}};

#pragma unroll
    for (int aR = 0; aR < 2; ++aR) {
#pragma unroll
        for (int aC = 0; aC < 2; ++aC) {
            int p = aR * 2 + aC;
            int nR = aR ? 3 : 2, nC = aC ? 3 : 2;
            int syb = aR ? u : (u + 1);
            int tyb = aC ? v : (v + 1);
#pragma unroll
            for (int jr = 0; jr < 3; ++jr) {
                if (jr >= nR) continue;
#pragma unroll
                for (int jc = 0; jc < 3; ++jc) {
                    if (jc >= nC) continue;
                    size_t addr = ((size_t)((p * 32 + b) * 34 + syb + jr) * 34 +
                                   (tyb + jc)) * 256 + ocb;
                    short8 rv = *reinterpret_cast<const short8*>((const char*)Y + addr * 2);
                    float f[8];
#pragma unroll
                    for (int k = 0; k < 8; ++k)
                        f[k] = __uint_as_float(((unsigned)(unsigned short)rv[k]) << 16);
#pragma unroll
                    for (int pm = 0; pm < 2; ++pm) {
                        int rw = aR ? RO[pm][jr] : RE[pm][jr];
                        if (rw == 0) continue;
#pragma unroll
                        for (int pn = 0; pn < 2; ++pn) {
                            int cw = aC ? RO[pn][jc] : RE[pn][jc];
                            if (cw == 0) continue;
                            float wgt = (float)(rw * cw);
#pragma unroll
                            for (int k = 0; k < 8; ++k) o[pm][pn][k] += wgt * f[k];
                        }
                    }
                }
            }
        }
    }

    const float s2 = 1.41421356237309515f;
#pragma unroll
    for (int k = 0; k < 8; ++k) {
        float bv = bias[ocb + k];
#pragma unroll
        for (int pm = 0; pm < 2; ++pm) {
            float y0 = o[pm][0][k] * 0.0625f + bv;
            float y1 = o[pm][1][k] * 0.0625f + bv;
            y0 = (y0 >= 0.f ? y0 : 0.2f * y0) * s2;
            y1 = (y1 >= 0.f ? y1 : 0.2f * y1) * s2;
            size_t base = (((size_t)b * OC + ocb + k) * OHW + 2 * u + pm) * OHW + 2 * v;
            *(f32x2*)(out + base) = (f32x2){y0, y1};
        }
    }
}

// ===========================================================================
// FALLBACK (verified R5 fused path, 272 us GEMM) — used if ws_size < WS_NEED.
__global__ __launch_bounds__(256) void wtrans_fb(const float* __restrict__ w,
                                                 __hip_bfloat16* __restrict__ Amat) {
    int t = blockIdx.x * blockDim.x + threadIdx.x;
    int ic = t & 511, oc = t >> 9;
    const float gain = 1.0f / sqrtf((float)(IC * 9));
    float wl[3][3];
    const float* wp = w + ((size_t)oc * IC + ic) * 9;
#pragma unroll
    for (int i = 0; i < 3; ++i)
#pragma unroll
        for (int j = 0; j < 3; ++j) wl[i][j] = wp[i * 3 + j] * gain;
    const float f1[4] = {1.f, 3.f, 3.f, 1.f};
    float g2[6][6];
#pragma unroll
    for (int s = 0; s < 6; ++s)
#pragma unroll
        for (int tt = 0; tt < 6; ++tt) {
            float acc = 0.f;
#pragma unroll
            for (int i = 0; i < 3; ++i)
#pragma unroll
                for (int j = 0; j < 3; ++j) {
                    int a = s - 2 + i, b = tt - 2 + j;
                    if (a >= 0 && a < 4 && b >= 0 && b < 4)
                        acc += wl[i][j] * f1[a] * f1[b] * 0.0625f;
                }
            g2[s][tt] = acc;
        }
#pragma unroll
    for (int pm = 0; pm < 2; ++pm)
#pragma unroll
        for (int pn = 0; pn < 2; ++pn)
#pragma unroll
            for (int k = 0; k < 3; ++k)
#pragma unroll
                for (int l = 0; l < 3; ++l) {
                    int p = pm * 2 + pn;
                    size_t idx = ((size_t)(oc * 4 + p) * 4608) + (k * 3 + l) * 512 + ic;
                    Amat[idx] = __float2bfloat16(g2[2 * k + 1 - pm][2 * l + 1 - pn]);
                }
}

__global__ __launch_bounds__(512, 2) void gemm_fb(const __hip_bfloat16* __restrict__ Amat,
                                                  const __hip_bfloat16* __restrict__ xcl,
                                                  const float* __restrict__ bias,
                                                  float* __restrict__ out) {
    __shared__ __align__(1024) char lds[4 * 32768];
    const int NT = 144;
    int bid = blockIdx.x;
    int mt = bid >> 7;
    int nt = (bid & 7) * 16 + ((bid >> 3) & 15);
    int tid = threadIdx.x;
    int wid = tid >> 6;
    int lane = tid & 63;
    int wr = wid >> 2, wc = wid & 3;
    int q = lane >> 4, lr = lane & 15;

    int rowS = tid >> 2, slt = tid & 3;
    int sgl = slt ^ ((rowS >> 1) & 3);
    const char* GA = (const char*)Amat + (size_t)mt * 256 * 9216;
    int offA0 = rowS * 9216 + sgl * 16;
    int offA1 = (rowS + 128) * 9216 + sgl * 16;
    int n0 = nt * 256 + rowS;
    int b0i = n0 >> 10, u0 = (n0 >> 5) & 31, v0 = n0 & 31;
    int n1 = n0 + 128;
    int b1i = n1 >> 10, u1 = (n1 >> 5) & 31, v1 = n1 & 31;
    const char* GB = (const char*)xcl;
    int offB0 = ((b0i * 34 + u0) * 34 + v0) * 1024 + sgl * 16;
    int offB1 = ((b1i * 34 + u1) * 34 + v1) * 1024 + sgl * 16;
    int dA0 = wid * 1024, dA1 = 8192 + wid * 1024;
    int dB0 = 16384 + wid * 1024, dB1 = 24576 + wid * 1024;

    int qs = (q ^ ((lr >> 1) & 3)) << 4;
    int A0 = (wr * 128 + lr) * 64 + qs;
    int B0 = 16384 + (wc * 64 + lr) * 64 + qs;

    f32x4 acc[8][4];
#pragma unroll
    for (int mi = 0; mi < 8; ++mi)
#pragma unroll
        for (int ni = 0; ni < 4; ++ni) acc[mi][ni] = (f32x4){0.f, 0.f, 0.f, 0.f};

    auto STAGE = [&](int ks, int bufi) {
        int kl = ks >> 4;
        int kh = (kl * 11) >> 5;
        int kw = kl - 3 * kh;
        int bko = (kh * 34 + kw) * 1024 + (ks & 15) * 64;
        int ao = ks * 64;
        char* L = lds + bufi * 32768;
        __builtin_amdgcn_global_load_lds(GPTR(GA + offA0 + ao), LPTR(L + dA0), 16, 0, 0);
        __builtin_amdgcn_global_load_lds(GPTR(GA + offA1 + ao), LPTR(L + dA1), 16, 0, 0);
        __builtin_amdgcn_global_load_lds(GPTR(GB + offB0 + bko), LPTR(L + dB0), 16, 0, 0);
        __builtin_amdgcn_global_load_lds(GPTR(GB + offB1 + bko), LPTR(L + dB1), 16, 0, 0);
    };

    short8 a0[8], b0[4], a1[8], b1[4];
#define READS_FB(SETA, SETB, TT)                                                \
    do {                                                                        \
        const char* L = lds + ((TT) & 3) * 32768;                               \
        _Pragma("unroll")                                                       \
        for (int mi = 0; mi < 8; ++mi) SETA[mi] = *(const short8*)(L + A0 + mi * 1024); \
        _Pragma("unroll")                                                       \
        for (int ni = 0; ni < 4; ++ni) SETB[ni] = *(const short8*)(L + B0 + ni * 1024); \
    } while (0)
#define MFMAS_FB(SETA, SETB)                                                    \
    do {                                                                        \
        __builtin_amdgcn_s_setprio(1);                                          \
        _Pragma("unroll")                                                       \
        for (int mi = 0; mi < 8; ++mi)                                          \
            _Pragma("unroll")                                                   \
            for (int ni = 0; ni < 4; ++ni)                                      \
                acc[mi][ni] = __builtin_amdgcn_mfma_f32_16x16x32_bf16(          \
                    SETA[mi], SETB[ni], acc[mi][ni], 0, 0, 0);                  \
        __builtin_amdgcn_s_setprio(0);                                          \
    } while (0)

    STAGE(0, 0);
    STAGE(1, 1);
    asm volatile("s_waitcnt vmcnt(4)" ::: "memory");
    __builtin_amdgcn_s_barrier();
    __builtin_amdgcn_sched_barrier(0);
    READS_FB(a0, b0, 0);

    for (int t = 0; t < NT; t += 2) {
        STAGE(t + 2 < NT ? t + 2 : NT - 1, (t + 2) & 3);
        asm volatile("s_waitcnt vmcnt(4)" ::: "memory");
        __builtin_amdgcn_s_barrier();
        __builtin_amdgcn_sched_barrier(0);
        READS_FB(a1, b1, t + 1);
        __builtin_amdgcn_sched_barrier(0);
        MFMAS_FB(a0, b0);

        STAGE(t + 3 < NT ? t + 3 : NT - 1, (t + 3) & 3);
        asm volatile("s_waitcnt vmcnt(4)" ::: "memory");
        __builtin_amdgcn_s_barrier();
        __builtin_amdgcn_sched_barrier(0);
        READS_FB(a0, b0, t + 2);
        __builtin_amdgcn_sched_barrier(0);
        MFMAS_FB(a1, b1);
    }
    asm volatile("s_waitcnt vmcnt(0)" ::: "memory");

    const float s2 = 1.41421356237309515f;
#pragma unroll
    for (int mi = 0; mi < 8; ++mi) {
        int oc = mt * 64 + wr * 32 + mi * 4 + q;
        float bv = bias[oc];
#pragma unroll
        for (int ni = 0; ni < 4; ++ni) {
            int n = nt * 256 + wc * 64 + ni * 16 + lr;
            int b = n >> 10, u = (n >> 5) & 31, v = n & 31;
            float y0 = acc[mi][ni][0] + bv;
            float y1 = acc[mi][ni][1] + bv;
            float y2 = acc[mi][ni][2] + bv;
            float y3 = acc[mi][ni][3] + bv;
            y0 = (y0 >= 0.f ? y0 : 0.2f * y0) * s2;
            y1 = (y1 >= 0.f ? y1 : 0.2f * y1) * s2;
            y2 = (y2 >= 0.f ? y2 : 0.2f * y2) * s2;
            y3 = (y3 >= 0.f ? y3 : 0.2f * y3) * s2;
            size_t base = (((size_t)b * OC + oc) * OHW + 2 * u) * OHW + 2 * v;
            *(f32x2*)(out + base)       = (f32x2){y0, y1};
            *(f32x2*)(out + base + OHW) = (f32x2){y2, y3};
        }
    }
#undef READS_FB
#undef MFMAS_FB
}

// ---------------------------------------------------------------------------
extern "C" void kernel_launch(void* const* d_in, const int* in_sizes, int n_in,
                              void* d_out, int out_size, void* d_ws, size_t ws_size,
                              hipStream_t stream) {
    const float* x    = (const float*)d_in[0];
    const float* w    = (const float*)d_in[1];
    const float* bias = (const float*)d_in[2];
    float* out = (float*)d_out;

    __hip_bfloat16* xcl = (__hip_bfloat16*)d_ws;
    xprep<<<32 * 34, 256, 0, stream>>>(x, xcl);

    if (ws_size >= WS_NEED) {
        __hip_bfloat16* A2 = (__hip_bfloat16*)((char*)d_ws + WS_A2_OFF);
        __hip_bfloat16* Y  = (__hip_bfloat16*)((char*)d_ws + WS_Y_OFF);
        wtrans2<<<(OC * IC) / 256, 256, 0, stream>>>(w, A2);
        gemm1<<<1160, 512, 0, stream>>>(A2, xcl, Y);
        fir2<<<4096, 256, 0, stream>>>(Y, bias, out);
    } else {
        __hip_bfloat16* Amat = (__hip_bfloat16*)((char*)d_ws + WS_AMAT_OFF);
        wtrans_fb<<<(OC * IC) / 256, 256, 0, stream>>>(w, Amat);
        gemm_fb<<<512, 512, 0, stream>>>(Amat, xcl, bias, out);
    }
}

// Round 17
// 290.373 us; speedup vs baseline: 1.0314x; 1.0314x over previous
//
#include <hip/hip_runtime.h>
#include <hip/hip_bf16.h>
#include <math.h>

// Problem constants
#define B_    32
#define IC    512
#define OC    256
#define HW    32
#define OHW   64

// ws layout (split path):
//   xcl at 0:         bf16 [32][34][34][512] = 37,879,808
//   A2  at 37879808:  bf16 [4][256][2048]    =  4,194,304
//   Y   at 42074112:  bf16 [4][32][34][34][256] = 75,890,688
#define WS_A2_OFF 37879808ull
#define WS_Y_OFF  42074112ull
#define WS_NEED   117964800ull
#define WS_AMAT_OFF 37879808ull

typedef __attribute__((ext_vector_type(8))) short short8;
typedef __attribute__((ext_vector_type(4))) float f32x4;
typedef __attribute__((ext_vector_type(2))) float f32x2;

#define GPTR(x) ((const __attribute__((address_space(1))) char*)(x))
#define LPTR(x) ((__attribute__((address_space(3))) char*)(x))

// ---------------------------------------------------------------------------
// x (fp32 NCHW) -> xcl (bf16, [b][34][34][512], zero halo).
__global__ __launch_bounds__(256) void xprep(const float* __restrict__ x,
                                             __hip_bfloat16* __restrict__ xcl) {
    int blk = blockIdx.x;            // 32*34 blocks
    int b = blk / 34, h = blk % 34;
    __hip_bfloat16* orow = xcl + (size_t)(b * 34 + h) * 34 * 512;
    int t = threadIdx.x;
    bool hin = (h >= 1 && h <= 32);

    for (int i = t; i < 2 * 512; i += 256) {
        int wsel = i >> 9, ic = i & 511;
        orow[(size_t)(wsel * 33) * 512 + ic] = __float2bfloat16(0.f);
    }

    __shared__ float ls[16][33];
    int icl_r = t >> 5, wv_r = t & 31;
    int wv_w = t >> 3, icl_w = t & 7;

    for (int ic0 = 0; ic0 < 512; ic0 += 16) {
        __syncthreads();
#pragma unroll
        for (int pp = 0; pp < 2; ++pp) {
            int icll = icl_r + pp * 8;
            float v = 0.f;
            if (hin) v = x[(((size_t)b * IC + ic0 + icll) * HW + (h - 1)) * HW + wv_r];
            ls[icll][wv_r] = v;
        }
        __syncthreads();
#pragma unroll
        for (int pp = 0; pp < 2; ++pp) {
            int icll = icl_w + pp * 8;
            orow[(size_t)(wv_w + 1) * 512 + ic0 + icll] = __float2bfloat16(ls[icll][wv_w]);
        }
    }
}

// ---------------------------------------------------------------------------
// Stage 0: A2[p][oc][kt*512+ic] = gain * w[oc][ic][a+2di][b+2dj]  (9 taps tot)
__global__ __launch_bounds__(256) void wtrans2(const float* __restrict__ w,
                                               __hip_bfloat16* __restrict__ A2) {
    int t = blockIdx.x * blockDim.x + threadIdx.x;  // 131072
    int ic = t & 511, oc = t >> 9;
    const float gain = 1.0f / sqrtf((float)(IC * 9));
    const float* wp = w + ((size_t)oc * IC + ic) * 9;
    float wl[3][3];
#pragma unroll
    for (int i = 0; i < 3; ++i)
#pragma unroll
        for (int j = 0; j < 3; ++j) wl[i][j] = wp[i * 3 + j] * gain;

    auto put = [&](int p, int kt, float v) {
        A2[((size_t)(p * 256 + oc) * 2048) + kt * 512 + ic] = __float2bfloat16(v);
    };
    put(0, 0, wl[0][0]); put(0, 1, wl[0][2]); put(0, 2, wl[2][0]); put(0, 3, wl[2][2]);
    put(1, 0, wl[0][1]); put(1, 1, wl[2][1]);
    put(2, 0, wl[1][0]); put(2, 1, wl[1][2]);
    put(3, 0, wl[1][1]);
}

// ---------------------------------------------------------------------------
// Stage 1 (R17): per-parity GEMM on the R4-VERIFIED geometry.
// 256(oc) x 256(n) tile, BK=32, 8 waves (2Mx4N), ring-4 LDS 128 KB,
// counted vmcnt(4), R4 zero-conflict swizzle, 1 barrier/tile.
// NT per parity {64,32,32,16}; 580 blocks (584 launched); XCD-contig mapping
// puts all 4 parities of one nt on one XCD (shared B-panel in L2).
__global__ __launch_bounds__(512, 2) void gemm1(const __hip_bfloat16* __restrict__ A2,
                                                const __hip_bfloat16* __restrict__ xcl,
                                                __hip_bfloat16* __restrict__ Y) {
    __shared__ __align__(1024) char lds[4 * 32768];

    int bid = blockIdx.x;            // 584 launched
    int x_ = bid & 7, j_ = bid >> 3;
    if (x_ < 4) { if (j_ >= 73) return; } else { if (j_ >= 72) return; }
    int idx = (x_ < 4) ? (x_ * 73 + j_) : (292 + (x_ - 4) * 72 + j_);   // 0..579
    int p = idx & 3;
    int nt = idx >> 2;               // 0..144
    const int NT = (p == 0) ? 64 : (p == 3) ? 16 : 32;

    int tid = threadIdx.x;
    int wid = tid >> 6;
    int lane = tid & 63;
    int wr = wid >> 2;               // 0..1  (M half: oc wr*128..+127)
    int wc = wid & 3;                // 0..3  (N quarter)
    int q = lane >> 4;
    int lr = lane & 15;

    // ---- staging constants (R4 swizzle folded into global source) ----
    int rowS = tid >> 2;             // 0..127 (second chunk: +128)
    int slt = tid & 3;
    int sgl = slt ^ ((rowS >> 1) & 3);   // rowS+128: same (128>>1 & 3 == 0)

    const char* GA = (const char*)A2 + (size_t)p * 256 * 4096;   // row pitch 4096 B
    int offA0 = rowS * 4096 + sgl * 16;
    int offA1 = (rowS + 128) * 4096 + sgl * 16;

    const char* GB = (const char*)xcl;
    int bt[2][2][2];                 // [chunk][di][dj]
#pragma unroll
    for (int i = 0; i < 2; ++i) {
        int n = nt * 256 + i * 128 + rowS;
        if (n > 36991) n = 36991;    // tail clamp (duplicate loads, unused)
        int bI = n / 1156, r_ = n - bI * 1156;
        int sy = r_ / 34, ty = r_ - sy * 34;
#pragma unroll
        for (int di = 0; di < 2; ++di)
#pragma unroll
            for (int dj = 0; dj < 2; ++dj) {
                int rr = sy - di; if (rr < 0) rr = 0;
                int cc = ty - dj; if (cc < 0) cc = 0;
                bt[i][di][dj] = ((bI * 34 + rr) * 34 + cc) * 1024 + sgl * 16;
            }
    }
    int dA0 = wid * 1024;            // + lane*16 by HW
    int dA1 = 8192 + wid * 1024;
    int dB0 = 16384 + wid * 1024;
    int dB1 = 24576 + wid * 1024;

    // ---- ds_read bases (R4 zero-conflict swizzle) ----
    int qs = (q ^ ((lr >> 1) & 3)) << 4;
    int A0 = (wr * 128 + lr) * 64 + qs;           // + mi*1024 imm
    int B0 = 16384 + (wc * 64 + lr) * 64 + qs;    // + ni*1024 imm

    f32x4 acc[8][4];
#pragma unroll
    for (int mi = 0; mi < 8; ++mi)
#pragma unroll
        for (int ni = 0; ni < 4; ++ni) acc[mi][ni] = (f32x4){0.f, 0.f, 0.f, 0.f};

    auto STAGE = [&](int ks, int bufi) {   // 4 loads/thread (R4 accounting)
        int tap = ks >> 4, icc = ks & 15;
        int di, dj;
        if (p == 0) { di = tap >> 1; dj = tap & 1; }
        else if (p == 1) { di = tap; dj = 0; }
        else if (p == 2) { di = 0; dj = tap; }
        else { di = 0; dj = 0; }
        int ao = ks * 64;
        int ico = icc * 64;
        char* L = lds + bufi * 32768;
        __builtin_amdgcn_global_load_lds(GPTR(GA + offA0 + ao), LPTR(L + dA0), 16, 0, 0);
        __builtin_amdgcn_global_load_lds(GPTR(GA + offA1 + ao), LPTR(L + dA1), 16, 0, 0);
        __builtin_amdgcn_global_load_lds(GPTR(GB + bt[0][di][dj] + ico), LPTR(L + dB0), 16, 0, 0);
        __builtin_amdgcn_global_load_lds(GPTR(GB + bt[1][di][dj] + ico), LPTR(L + dB1), 16, 0, 0);
    };

    STAGE(0, 0);
    STAGE(1, 1);

    for (int t = 0; t < NT; ++t) {
        asm volatile("s_waitcnt vmcnt(4)" ::: "memory");   // tile t landed
        __builtin_amdgcn_s_barrier();
        __builtin_amdgcn_sched_barrier(0);

        STAGE(t + 2 < NT ? t + 2 : NT - 1, (t + 2) & 3);

        const char* Lc = lds + (t & 3) * 32768;
        short8 aF[8], bF[4];
#pragma unroll
        for (int mi = 0; mi < 8; ++mi) aF[mi] = *(const short8*)(Lc + A0 + mi * 1024);
#pragma unroll
        for (int ni = 0; ni < 4; ++ni) bF[ni] = *(const short8*)(Lc + B0 + ni * 1024);

        __builtin_amdgcn_s_setprio(1);
#pragma unroll
        for (int mi = 0; mi < 8; ++mi)
#pragma unroll
            for (int ni = 0; ni < 4; ++ni)
                acc[mi][ni] = __builtin_amdgcn_mfma_f32_16x16x32_bf16(
                    aF[mi], bF[ni], acc[mi][ni], 0, 0, 0);
        __builtin_amdgcn_s_setprio(0);
    }
    asm volatile("s_waitcnt vmcnt(0)" ::: "memory");

    // ---- epilogue: C col = n (lane&15), row = oc; ushort4 per (mi,ni) ----
#pragma unroll
    for (int ni = 0; ni < 4; ++ni) {
        int n = nt * 256 + wc * 64 + ni * 16 + lr;
        if (n < 36992) {
            int bI = n / 1156, r2 = n - bI * 1156;
            int sy = r2 / 34, ty = r2 - sy * 34;
            size_t rowbase = ((size_t)((p * 32 + bI) * 34 + sy) * 34 + ty) * 256;
#pragma unroll
            for (int mi = 0; mi < 8; ++mi) {
                int oc = wr * 128 + mi * 16 + (lane >> 4) * 4;
                ushort4 st;
                __hip_bfloat16 h0 = __float2bfloat16(acc[mi][ni][0]);
                __hip_bfloat16 h1 = __float2bfloat16(acc[mi][ni][1]);
                __hip_bfloat16 h2 = __float2bfloat16(acc[mi][ni][2]);
                __hip_bfloat16 h3 = __float2bfloat16(acc[mi][ni][3]);
                st.x = *reinterpret_cast<unsigned short*>(&h0);
                st.y = *reinterpret_cast<unsigned short*>(&h1);
                st.z = *reinterpret_cast<unsigned short*>(&h2);
                st.w = *reinterpret_cast<unsigned short*>(&h3);
                *reinterpret_cast<ushort4*>((char*)Y + (rowbase + oc) * 2) = st;
            }
        }
    }
}

// ---------------------------------------------------------------------------
// Stage 2: depthwise FIR + bias + leaky*sqrt(2). Y is zero-padded (verified).
__global__ __launch_bounds__(256) void fir2(const __hip_bfloat16* __restrict__ Y,
                                            const float* __restrict__ bias,
                                            float* __restrict__ out) {
    int bid = blockIdx.x;            // 4096 = b(32) * u(32) * ocq(4)
    int b = bid >> 7, u = (bid >> 2) & 31, ocq = bid & 3;
    int tid = threadIdx.x;
    int oct = tid >> 5, v = tid & 31;
    int ocb = ocq * 64 + oct * 8;

    float o[2][2][8];
#pragma unroll
    for (int pm = 0; pm < 2; ++pm)
#pragma unroll
        for (int pn = 0; pn < 2; ++pn)
#pragma unroll
            for (int k = 0; k < 8; ++k) o[pm][pn][k] = 0.f;

    const int RE[2][2] = {{3, 1}, {1, 3}};
    const int RO[2][3] = {{1, 3, 0}, {0, 3, 1}};

#pragma unroll
    for (int aR = 0; aR < 2; ++aR) {
#pragma unroll
        for (int aC = 0; aC < 2; ++aC) {
            int p = aR * 2 + aC;
            int nR = aR ? 3 : 2, nC = aC ? 3 : 2;
            int syb = aR ? u : (u + 1);
            int tyb = aC ? v : (v + 1);
#pragma unroll
            for (int jr = 0; jr < 3; ++jr) {
                if (jr >= nR) continue;
#pragma unroll
                for (int jc = 0; jc < 3; ++jc) {
                    if (jc >= nC) continue;
                    size_t addr = ((size_t)((p * 32 + b) * 34 + syb + jr) * 34 +
                                   (tyb + jc)) * 256 + ocb;
                    short8 rv = *reinterpret_cast<const short8*>((const char*)Y + addr * 2);
                    float f[8];
#pragma unroll
                    for (int k = 0; k < 8; ++k)
                        f[k] = __uint_as_float(((unsigned)(unsigned short)rv[k]) << 16);
#pragma unroll
                    for (int pm = 0; pm < 2; ++pm) {
                        int rw = aR ? RO[pm][jr] : RE[pm][jr];
                        if (rw == 0) continue;
#pragma unroll
                        for (int pn = 0; pn < 2; ++pn) {
                            int cw = aC ? RO[pn][jc] : RE[pn][jc];
                            if (cw == 0) continue;
                            float wgt = (float)(rw * cw);
#pragma unroll
                            for (int k = 0; k < 8; ++k) o[pm][pn][k] += wgt * f[k];
                        }
                    }
                }
            }
        }
    }

    const float s2 = 1.41421356237309515f;
#pragma unroll
    for (int k = 0; k < 8; ++k) {
        float bv = bias[ocb + k];
#pragma unroll
        for (int pm = 0; pm < 2; ++pm) {
            float y0 = o[pm][0][k] * 0.0625f + bv;
            float y1 = o[pm][1][k] * 0.0625f + bv;
            y0 = (y0 >= 0.f ? y0 : 0.2f * y0) * s2;
            y1 = (y1 >= 0.f ? y1 : 0.2f * y1) * s2;
            size_t base = (((size_t)b * OC + ocb + k) * OHW + 2 * u + pm) * OHW + 2 * v;
            *(f32x2*)(out + base) = (f32x2){y0, y1};
        }
    }
}

// ---------------------------------------------------------------------------
extern "C" void kernel_launch(void* const* d_in, const int* in_sizes, int n_in,
                              void* d_out, int out_size, void* d_ws, size_t ws_size,
                              hipStream_t stream) {
    const float* x    = (const float*)d_in[0];
    const float* w    = (const float*)d_in[1];
    const float* bias = (const float*)d_in[2];
    float* out = (float*)d_out;

    __hip_bfloat16* xcl = (__hip_bfloat16*)d_ws;
    __hip_bfloat16* A2  = (__hip_bfloat16*)((char*)d_ws + WS_A2_OFF);
    __hip_bfloat16* Y   = (__hip_bfloat16*)((char*)d_ws + WS_Y_OFF);

    xprep<<<32 * 34, 256, 0, stream>>>(x, xcl);
    wtrans2<<<(OC * IC) / 256, 256, 0, stream>>>(w, A2);
    gemm1<<<584, 512, 0, stream>>>(A2, xcl, Y);
    fir2<<<4096, 256, 0, stream>>>(Y, bias, out);
}

// Round 18
// 227.831 us; speedup vs baseline: 1.3146x; 1.2745x over previous
//
#include <hip/hip_runtime.h>
#include <hip/hip_bf16.h>
#include <math.h>

// Problem constants
#define B_    32
#define IC    512
#define OC    256
#define HW    32
#define OHW   64

// ws layout (split path):
//   xcl at 0:         bf16 [32][34][34][512] = 37,879,808
//   A2  at 37879808:  bf16 [4][256][2048]    =  4,194,304
//   Y   at 42074112:  bf16 [4][32][34][34][256] = 75,890,688
#define WS_A2_OFF 37879808ull
#define WS_Y_OFF  42074112ull

typedef __attribute__((ext_vector_type(8))) short short8;
typedef __attribute__((ext_vector_type(4))) float f32x4;
typedef __attribute__((ext_vector_type(2))) float f32x2;

#define GPTR(x) ((const __attribute__((address_space(1))) char*)(x))
#define LPTR(x) ((__attribute__((address_space(3))) char*)(x))

// ---------------------------------------------------------------------------
// x (fp32 NCHW) -> xcl (bf16, [b][34][34][512], zero halo).
__global__ __launch_bounds__(256) void xprep(const float* __restrict__ x,
                                             __hip_bfloat16* __restrict__ xcl) {
    int blk = blockIdx.x;            // 32*34 blocks
    int b = blk / 34, h = blk % 34;
    __hip_bfloat16* orow = xcl + (size_t)(b * 34 + h) * 34 * 512;
    int t = threadIdx.x;
    bool hin = (h >= 1 && h <= 32);

    for (int i = t; i < 2 * 512; i += 256) {
        int wsel = i >> 9, ic = i & 511;
        orow[(size_t)(wsel * 33) * 512 + ic] = __float2bfloat16(0.f);
    }

    __shared__ float ls[16][33];
    int icl_r = t >> 5, wv_r = t & 31;
    int wv_w = t >> 3, icl_w = t & 7;

    for (int ic0 = 0; ic0 < 512; ic0 += 16) {
        __syncthreads();
#pragma unroll
        for (int pp = 0; pp < 2; ++pp) {
            int icll = icl_r + pp * 8;
            float v = 0.f;
            if (hin) v = x[(((size_t)b * IC + ic0 + icll) * HW + (h - 1)) * HW + wv_r];
            ls[icll][wv_r] = v;
        }
        __syncthreads();
#pragma unroll
        for (int pp = 0; pp < 2; ++pp) {
            int icll = icl_w + pp * 8;
            orow[(size_t)(wv_w + 1) * 512 + ic0 + icll] = __float2bfloat16(ls[icll][wv_w]);
        }
    }
}

// ---------------------------------------------------------------------------
// Stage 0: A2[p][oc][kt*512+ic] = gain * w[oc][ic][a+2di][b+2dj]  (9 taps tot)
__global__ __launch_bounds__(256) void wtrans2(const float* __restrict__ w,
                                               __hip_bfloat16* __restrict__ A2) {
    int t = blockIdx.x * blockDim.x + threadIdx.x;  // 131072
    int ic = t & 511, oc = t >> 9;
    const float gain = 1.0f / sqrtf((float)(IC * 9));
    const float* wp = w + ((size_t)oc * IC + ic) * 9;
    float wl[3][3];
#pragma unroll
    for (int i = 0; i < 3; ++i)
#pragma unroll
        for (int j = 0; j < 3; ++j) wl[i][j] = wp[i * 3 + j] * gain;

    auto put = [&](int p, int kt, float v) {
        A2[((size_t)(p * 256 + oc) * 2048) + kt * 512 + ic] = __float2bfloat16(v);
    };
    put(0, 0, wl[0][0]); put(0, 1, wl[0][2]); put(0, 2, wl[2][0]); put(0, 3, wl[2][2]);
    put(1, 0, wl[0][1]); put(1, 1, wl[2][1]);
    put(2, 0, wl[1][0]); put(2, 1, wl[1][2]);
    put(3, 0, wl[1][1]);
}

// ---------------------------------------------------------------------------
// Stage 1 (R18): PERSISTENT static-balanced schedule. 256 blocks (1/CU, all
// resident, no dispatch rounds). Unit = (parity p, n-tile nt) with the R4
// loop (256x256, BK=32, 8 waves, ring-4, vmcnt(4), zero-conflict swizzle).
//   blocks 0..144:  {p0 nt=b (NT=64), p3 nt=b (NT=16)} = 80 tiles (shared
//                   B-panel -> L2 reuse)
//   blocks 145..212: three p1/p2 units (96 tiles); 213..255: two (64 tiles)
// Makespan 96 tiles vs R17's effective ~205. Unit-boundary race safety:
// last reads hit bufs 2,3; next prologue writes bufs 0,1; first t=0 barrier
// precedes the first buf-2 overwrite. t=0 vmcnt(4) also drains the previous
// epilogue's stores (stores count in vmcnt) — conservative, correct.
__global__ __launch_bounds__(512, 2) void gemm1(const __hip_bfloat16* __restrict__ A2,
                                                const __hip_bfloat16* __restrict__ xcl,
                                                __hip_bfloat16* __restrict__ Y) {
    __shared__ __align__(1024) char lds[4 * 32768];

    int blk = blockIdx.x;            // 0..255
    int tid = threadIdx.x;
    int wid = tid >> 6;
    int lane = tid & 63;
    int wr = wid >> 2;               // 0..1  (M half: oc wr*128..+127)
    int wc = wid & 3;                // 0..3  (N quarter)
    int q = lane >> 4;
    int lr = lane & 15;

    int rowS = tid >> 2;             // 0..127
    int slt = tid & 3;
    int sgl = slt ^ ((rowS >> 1) & 3);

    int dA0 = wid * 1024;            // + lane*16 by HW
    int dA1 = 8192 + wid * 1024;
    int dB0 = 16384 + wid * 1024;
    int dB1 = 24576 + wid * 1024;

    int qs = (q ^ ((lr >> 1) & 3)) << 4;
    int A0 = (wr * 128 + lr) * 64 + qs;           // + mi*1024 imm
    int B0 = 16384 + (wc * 64 + lr) * 64 + qs;    // + ni*1024 imm

    // ---- static unit list (uniform scalars) ----
    int nu, ups[3], unts[3], uNTs[3];
    if (blk < 145) {
        nu = 2;
        ups[0] = 0; unts[0] = blk; uNTs[0] = 64;
        ups[1] = 3; unts[1] = blk; uNTs[1] = 16;
    } else {
        int qb = blk - 145;
        nu = 0;
#pragma unroll
        for (int j = 0; j < 3; ++j) {
            int i = qb + 111 * j;
            if (i < 290) {
                ups[nu] = (i < 145) ? 1 : 2;
                unts[nu] = (i < 145) ? i : (i - 145);
                uNTs[nu] = 32;
                ++nu;
            }
        }
    }

    const char* GB = (const char*)xcl;

    for (int uu = 0; uu < nu; ++uu) {
        int p = ups[uu], nt = unts[uu], NT = uNTs[uu];

        const char* GA = (const char*)A2 + (size_t)p * 256 * 4096;  // pitch 4096
        int offA0 = rowS * 4096 + sgl * 16;
        int offA1 = (rowS + 128) * 4096 + sgl * 16;

        int bt[2][2][2];             // [chunk][di][dj] tap base addresses
#pragma unroll
        for (int i = 0; i < 2; ++i) {
            int n = nt * 256 + i * 128 + rowS;
            if (n > 36991) n = 36991;
            int bI = n / 1156, r_ = n - bI * 1156;
            int sy = r_ / 34, ty = r_ - sy * 34;
#pragma unroll
            for (int di = 0; di < 2; ++di)
#pragma unroll
                for (int dj = 0; dj < 2; ++dj) {
                    int rr = sy - di; if (rr < 0) rr = 0;
                    int cc = ty - dj; if (cc < 0) cc = 0;
                    bt[i][di][dj] = ((bI * 34 + rr) * 34 + cc) * 1024 + sgl * 16;
                }
        }

        f32x4 acc[8][4];
#pragma unroll
        for (int mi = 0; mi < 8; ++mi)
#pragma unroll
            for (int ni = 0; ni < 4; ++ni) acc[mi][ni] = (f32x4){0.f, 0.f, 0.f, 0.f};

        auto STAGE = [&](int ks, int bufi) {
            int tap = ks >> 4, icc = ks & 15;
            int di, dj;
            if (p == 0) { di = tap >> 1; dj = tap & 1; }
            else if (p == 1) { di = tap; dj = 0; }
            else if (p == 2) { di = 0; dj = tap; }
            else { di = 0; dj = 0; }
            int ao = ks * 64;
            int ico = icc * 64;
            char* L = lds + bufi * 32768;
            __builtin_amdgcn_global_load_lds(GPTR(GA + offA0 + ao), LPTR(L + dA0), 16, 0, 0);
            __builtin_amdgcn_global_load_lds(GPTR(GA + offA1 + ao), LPTR(L + dA1), 16, 0, 0);
            __builtin_amdgcn_global_load_lds(GPTR(GB + bt[0][di][dj] + ico), LPTR(L + dB0), 16, 0, 0);
            __builtin_amdgcn_global_load_lds(GPTR(GB + bt[1][di][dj] + ico), LPTR(L + dB1), 16, 0, 0);
        };

        STAGE(0, 0);
        STAGE(1, 1);

        for (int t = 0; t < NT; ++t) {
            asm volatile("s_waitcnt vmcnt(4)" ::: "memory");   // tile t landed
            __builtin_amdgcn_s_barrier();
            __builtin_amdgcn_sched_barrier(0);

            STAGE(t + 2 < NT ? t + 2 : NT - 1, (t + 2) & 3);

            const char* Lc = lds + (t & 3) * 32768;
            short8 aF[8], bF[4];
#pragma unroll
            for (int mi = 0; mi < 8; ++mi) aF[mi] = *(const short8*)(Lc + A0 + mi * 1024);
#pragma unroll
            for (int ni = 0; ni < 4; ++ni) bF[ni] = *(const short8*)(Lc + B0 + ni * 1024);

            __builtin_amdgcn_s_setprio(1);
#pragma unroll
            for (int mi = 0; mi < 8; ++mi)
#pragma unroll
                for (int ni = 0; ni < 4; ++ni)
                    acc[mi][ni] = __builtin_amdgcn_mfma_f32_16x16x32_bf16(
                        aF[mi], bF[ni], acc[mi][ni], 0, 0, 0);
            __builtin_amdgcn_s_setprio(0);
        }
        asm volatile("s_waitcnt vmcnt(0)" ::: "memory");   // drain clamped stages

        // ---- epilogue: ushort4 per (mi,ni) ----
#pragma unroll
        for (int ni = 0; ni < 4; ++ni) {
            int n = nt * 256 + wc * 64 + ni * 16 + lr;
            if (n < 36992) {
                int bI = n / 1156, r2 = n - bI * 1156;
                int sy = r2 / 34, ty = r2 - sy * 34;
                size_t rowbase = ((size_t)((p * 32 + bI) * 34 + sy) * 34 + ty) * 256;
#pragma unroll
                for (int mi = 0; mi < 8; ++mi) {
                    int oc = wr * 128 + mi * 16 + (lane >> 4) * 4;
                    ushort4 st;
                    __hip_bfloat16 h0 = __float2bfloat16(acc[mi][ni][0]);
                    __hip_bfloat16 h1 = __float2bfloat16(acc[mi][ni][1]);
                    __hip_bfloat16 h2 = __float2bfloat16(acc[mi][ni][2]);
                    __hip_bfloat16 h3 = __float2bfloat16(acc[mi][ni][3]);
                    st.x = *reinterpret_cast<unsigned short*>(&h0);
                    st.y = *reinterpret_cast<unsigned short*>(&h1);
                    st.z = *reinterpret_cast<unsigned short*>(&h2);
                    st.w = *reinterpret_cast<unsigned short*>(&h3);
                    *reinterpret_cast<ushort4*>((char*)Y + (rowbase + oc) * 2) = st;
                }
            }
        }
    }
}

// ---------------------------------------------------------------------------
// Stage 2: depthwise FIR + bias + leaky*sqrt(2). Y is zero-padded (verified).
__global__ __launch_bounds__(256) void fir2(const __hip_bfloat16* __restrict__ Y,
                                            const float* __restrict__ bias,
                                            float* __restrict__ out) {
    int bid = blockIdx.x;            // 4096 = b(32) * u(32) * ocq(4)
    int b = bid >> 7, u = (bid >> 2) & 31, ocq = bid & 3;
    int tid = threadIdx.x;
    int oct = tid >> 5, v = tid & 31;
    int ocb = ocq * 64 + oct * 8;

    float o[2][2][8];
#pragma unroll
    for (int pm = 0; pm < 2; ++pm)
#pragma unroll
        for (int pn = 0; pn < 2; ++pn)
#pragma unroll
            for (int k = 0; k < 8; ++k) o[pm][pn][k] = 0.f;

    const int RE[2][2] = {{3, 1}, {1, 3}};
    const int RO[2][3] = {{1, 3, 0}, {0, 3, 1}};

#pragma unroll
    for (int aR = 0; aR < 2; ++aR) {
#pragma unroll
        for (int aC = 0; aC < 2; ++aC) {
            int p = aR * 2 + aC;
            int nR = aR ? 3 : 2, nC = aC ? 3 : 2;
            int syb = aR ? u : (u + 1);
            int tyb = aC ? v : (v + 1);
#pragma unroll
            for (int jr = 0; jr < 3; ++jr) {
                if (jr >= nR) continue;
#pragma unroll
                for (int jc = 0; jc < 3; ++jc) {
                    if (jc >= nC) continue;
                    size_t addr = ((size_t)((p * 32 + b) * 34 + syb + jr) * 34 +
                                   (tyb + jc)) * 256 + ocb;
                    short8 rv = *reinterpret_cast<const short8*>((const char*)Y + addr * 2);
                    float f[8];
#pragma unroll
                    for (int k = 0; k < 8; ++k)
                        f[k] = __uint_as_float(((unsigned)(unsigned short)rv[k]) << 16);
#pragma unroll
                    for (int pm = 0; pm < 2; ++pm) {
                        int rw = aR ? RO[pm][jr] : RE[pm][jr];
                        if (rw == 0) continue;
#pragma unroll
                        for (int pn = 0; pn < 2; ++pn) {
                            int cw = aC ? RO[pn][jc] : RE[pn][jc];
                            if (cw == 0) continue;
                            float wgt = (float)(rw * cw);
#pragma unroll
                            for (int k = 0; k < 8; ++k) o[pm][pn][k] += wgt * f[k];
                        }
                    }
                }
            }
        }
    }

    const float s2 = 1.41421356237309515f;
#pragma unroll
    for (int k = 0; k < 8; ++k) {
        float bv = bias[ocb + k];
#pragma unroll
        for (int pm = 0; pm < 2; ++pm) {
            float y0 = o[pm][0][k] * 0.0625f + bv;
            float y1 = o[pm][1][k] * 0.0625f + bv;
            y0 = (y0 >= 0.f ? y0 : 0.2f * y0) * s2;
            y1 = (y1 >= 0.f ? y1 : 0.2f * y1) * s2;
            size_t base = (((size_t)b * OC + ocb + k) * OHW + 2 * u + pm) * OHW + 2 * v;
            *(f32x2*)(out + base) = (f32x2){y0, y1};
        }
    }
}

// ---------------------------------------------------------------------------
extern "C" void kernel_launch(void* const* d_in, const int* in_sizes, int n_in,
                              void* d_out, int out_size, void* d_ws, size_t ws_size,
                              hipStream_t stream) {
    const float* x    = (const float*)d_in[0];
    const float* w    = (const float*)d_in[1];
    const float* bias = (const float*)d_in[2];
    float* out = (float*)d_out;

    __hip_bfloat16* xcl = (__hip_bfloat16*)d_ws;
    __hip_bfloat16* A2  = (__hip_bfloat16*)((char*)d_ws + WS_A2_OFF);
    __hip_bfloat16* Y   = (__hip_bfloat16*)((char*)d_ws + WS_Y_OFF);

    xprep<<<32 * 34, 256, 0, stream>>>(x, xcl);
    wtrans2<<<(OC * IC) / 256, 256, 0, stream>>>(w, A2);
    gemm1<<<256, 512, 0, stream>>>(A2, xcl, Y);
    fir2<<<4096, 256, 0, stream>>>(Y, bias, out);
}